// Round 1
// baseline (1390.110 us; speedup 1.0000x reference)
//
#include <hip/hip_runtime.h>

// DoubleConv: hypernet-generated radius-interpolated 3x3 conv x2 + per-item BN+ReLU.
// Round 1: correct fp32 baseline, tiled per-column GEMM.

#define HOS   64
#define NRAD  8
#define SD    6
#define HD    128
#define C128  128      // CIN == COUT == 128
#define IMGH  256
#define IMGW  256
#define NB    2
#define HYPER_OUT 294912   // 64*64*8*3*3
#define BN_EPS 1e-5f

// ---------------- e-MLPs: e_all[16][128], row r = item*8 + conv*4 + n ----------------
__global__ __launch_bounds__(128) void k_mlp(
    const float* __restrict__ seidel,
    const float* __restrict__ m1_w1, const float* __restrict__ m1_b1,
    const float* __restrict__ m1_w2, const float* __restrict__ m1_b2,
    const float* __restrict__ m2_w1, const float* __restrict__ m2_b1,
    const float* __restrict__ m2_w2, const float* __restrict__ m2_b2,
    float* __restrict__ e_all)
{
  int b = blockIdx.x;                 // 16 blocks
  int item = b >> 3, conv = (b >> 2) & 1, n = b & 3;
  const float* w1 = conv ? m2_w1 : m1_w1;
  const float* b1 = conv ? m2_b1 : m1_b1;
  const float* w2 = conv ? m2_w2 : m1_w2;
  const float* b2 = conv ? m2_b2 : m1_b2;
  int t = threadIdx.x;                // 128
  __shared__ float e1[HD];
  float s = b1[n*HD + t];
  #pragma unroll
  for (int i = 0; i < SD; ++i) s = fmaf(seidel[item*SD + i], w1[(n*SD + i)*HD + t], s);
  e1[t] = fmaxf(s, 0.f);
  __syncthreads();
  float s2 = b2[n*HD + t];
  for (int i = 0; i < HD; ++i) s2 = fmaf(e1[i], w2[(n*HD + i)*HD + t], s2);
  e_all[b*HD + t] = fmaxf(s2, 0.f);
}

// ---------------- hyper GEMM + scatter into weight layout ----------------
// wbase layout: [conv][item][nr][ki][kj][i(128)][o(128)]
__global__ __launch_bounds__(256) void k_hyper(
    const float* __restrict__ e_all, const float* __restrict__ hyper_w,
    const float* __restrict__ hyper_b, float* __restrict__ wbase)
{
  __shared__ float es[16*HD];
  int t = threadIdx.x;
  for (int f = t; f < 16*HD; f += 256) es[f] = e_all[f];
  __syncthreads();
  int j = blockIdx.x*256 + t;         // 1152 blocks * 256 = 294912 exactly
  float val[16];
  #pragma unroll
  for (int r = 0; r < 16; ++r) val[r] = 0.f;
  for (int i = 0; i < HD; ++i) {
    float hw = hyper_w[(size_t)i*HYPER_OUT + j];
    #pragma unroll
    for (int r = 0; r < 16; ++r) val[r] = fmaf(es[r*HD + i], hw, val[r]);
  }
  float bias = hyper_b[j];
  int kj = j % 3; int tt = j / 3;
  int ki = tt % 3; tt /= 3;
  int nr = tt & 7; tt >>= 3;
  int v  = tt & 63; int u = tt >> 6;
  #pragma unroll
  for (int r = 0; r < 16; ++r) {
    int item = r >> 3, conv = (r >> 2) & 1, n = r & 3;
    int rr = n >> 1, cc = n & 1;
    int o  = rr*64 + u;
    int ii = cc*64 + v;
    size_t off = ((((((size_t)conv*2 + item)*8 + nr)*3 + ki)*3 + kj)*128 + ii)*128 + o;
    wbase[off] = val[r] + bias;
  }
}

// ---------------- transpose x: [item][c][h][w] -> [item][w][c][h] ----------------
__global__ __launch_bounds__(256) void k_transpose(
    const float* __restrict__ src, float* __restrict__ dst)
{
  __shared__ float tile[64][65];
  int ch = blockIdx.z & 127, item = blockIdx.z >> 7;
  int w0 = blockIdx.x*64, h0 = blockIdx.y*64;
  int t = threadIdx.x;
  int hh = t >> 2, wr = (t & 3)*16;
  const float* sp = src + (((size_t)item*C128 + ch)*IMGH + h0 + hh)*IMGW + w0 + wr;
  #pragma unroll
  for (int k = 0; k < 16; k += 4) {
    float4 v = *reinterpret_cast<const float4*>(sp + k);
    tile[wr+k+0][hh] = v.x; tile[wr+k+1][hh] = v.y;
    tile[wr+k+2][hh] = v.z; tile[wr+k+3][hh] = v.w;
  }
  __syncthreads();
  int ww = t >> 2, hr = (t & 3)*16;
  float* dp = dst + (((size_t)item*IMGW + w0 + ww)*C128 + ch)*IMGH + h0 + hr;
  #pragma unroll
  for (int k = 0; k < 16; k += 4) {
    float4 v;
    v.x = tile[ww][hr+k]; v.y = tile[ww][hr+k+1];
    v.z = tile[ww][hr+k+2]; v.w = tile[ww][hr+k+3];
    *reinterpret_cast<float4*>(dp + k) = v;
  }
}

// ---------------- conv: per-column GEMM with on-the-fly radius lerp ----------------
// src_t: [item][w][c][h] ; dst_t: [item][w][o][h] (pre-BN)
// grid: (w=256, h-half=2, item=2), block 256.
template<bool BN_IN>
__global__ __launch_bounds__(256) void k_conv(
    const float* __restrict__ src_t, const float* __restrict__ wconv,
    const float* __restrict__ bn_a, const float* __restrict__ bn_c,
    float* __restrict__ dst_t)
{
  __shared__ float As[64*132];   // [i(64)][hw(130) pad 132]
  __shared__ float Bs[32*132];   // [i(32)][o(128) pad 132]
  int w = blockIdx.x, hb = blockIdx.y, item = blockIdx.z;
  int t = threadIdx.x;
  int tx = t & 15;               // h: thread handles h = tx + 16*k, k=0..7
  int ty = t >> 4;               // o: o = ty*8 + y, y=0..7
  // trilinear radius interpolation (align_corners=False), clamp [0,7]
  float pos = (w + 0.5f)*(8.0f/256.0f) - 0.5f;
  pos = fminf(fmaxf(pos, 0.f), 7.f);
  int   i0 = (int)pos;
  float fr = pos - (float)i0;
  int   i1 = min(i0 + 1, 7);

  float acc[8][8];
  #pragma unroll
  for (int a = 0; a < 8; ++a)
    #pragma unroll
    for (int b = 0; b < 8; ++b) acc[a][b] = 0.f;

  for (int kj = 0; kj < 3; ++kj) {
    int wc = w + kj - 1;
    bool valid = (wc >= 0) && (wc < IMGW);     // zero pad in W (block-uniform)
    const float* sbase = src_t + ((size_t)item*IMGW + (valid ? wc : 0))*C128*IMGH;
    for (int ih = 0; ih < 2; ++ih) {           // channel half: 64
      __syncthreads();                          // protect As from lagging readers
      for (int f = t; f < 64*130; f += 256) {
        int ii = f / 130, hw = f - ii*130;
        float vv = 0.f;
        if (valid) {
          int hg = (hb*128 + hw - 1) & 255;     // circular pad in H
          int c  = ih*64 + ii;
          vv = sbase[(size_t)c*IMGH + hg];
          if (BN_IN) vv = fmaxf(fmaf(bn_a[item*C128 + c], vv, bn_c[item*C128 + c]), 0.f);
        }
        As[ii*132 + hw] = vv;
      }
      for (int ki = 0; ki < 3; ++ki) {
        for (int ic = 0; ic < 2; ++ic) {        // 32-channel chunk within the half
          __syncthreads();                       // As ready / Bs readers done
          const float* wb0 = wconv + ((((size_t)item*8 + i0)*3 + ki)*3 + kj)*16384;
          const float* wb1 = wconv + ((((size_t)item*8 + i1)*3 + ki)*3 + kj)*16384;
          for (int f = t; f < 32*128; f += 256) {
            int ii = f >> 7, o = f & 127;
            int idx = (ih*64 + ic*32 + ii)*128 + o;
            float w0v = wb0[idx], w1v = wb1[idx];
            Bs[ii*132 + o] = fmaf(fr, w1v - w0v, w0v);
          }
          __syncthreads();
          int arow = ic*32;
          for (int ii = 0; ii < 32; ++ii) {
            float a[8], b[8];
            #pragma unroll
            for (int k = 0; k < 8; ++k) a[k] = As[(arow + ii)*132 + tx + 16*k + ki];
            const float4* bp = reinterpret_cast<const float4*>(&Bs[ii*132 + ty*8]);
            float4 b0 = bp[0], b1 = bp[1];
            b[0]=b0.x; b[1]=b0.y; b[2]=b0.z; b[3]=b0.w;
            b[4]=b1.x; b[5]=b1.y; b[6]=b1.z; b[7]=b1.w;
            #pragma unroll
            for (int k = 0; k < 8; ++k)
              #pragma unroll
              for (int y = 0; y < 8; ++y)
                acc[k][y] = fmaf(a[k], b[y], acc[k][y]);
          }
        }
      }
    }
  }
  // store pre-BN output, coalesced in h
  float* dp = dst_t + ((size_t)item*IMGW + w)*C128*IMGH + (size_t)hb*128 + tx;
  #pragma unroll
  for (int y = 0; y < 8; ++y) {
    float* rowp = dp + (size_t)(ty*8 + y)*IMGH;
    #pragma unroll
    for (int k = 0; k < 8; ++k) rowp[16*k] = acc[k][y];
  }
}

// ---------------- BN stats -> affine (a, c): deterministic tree reduction ----------------
__global__ __launch_bounds__(256) void k_stats(
    const float* __restrict__ y_t, const float* __restrict__ gamma,
    const float* __restrict__ beta, float* __restrict__ bn_a, float* __restrict__ bn_c)
{
  int item = blockIdx.x >> 7, ch = blockIdx.x & 127;
  int t = threadIdx.x;                 // t = h index
  float s = 0.f, s2 = 0.f;
  const float* base = y_t + ((size_t)item*IMGW*C128 + ch)*IMGH;
  for (int w = 0; w < IMGW; ++w) {
    float v = base[(size_t)w*C128*IMGH + t];
    s += v; s2 = fmaf(v, v, s2);
  }
  #pragma unroll
  for (int m = 32; m; m >>= 1) { s += __shfl_down(s, m); s2 += __shfl_down(s2, m); }
  __shared__ float rs[4], rs2[4];
  if ((t & 63) == 0) { rs[t >> 6] = s; rs2[t >> 6] = s2; }
  __syncthreads();
  if (t == 0) {
    s  = rs[0] + rs[1] + rs[2] + rs[3];
    s2 = rs2[0] + rs2[1] + rs2[2] + rs2[3];
    float mu  = s  * (1.f/65536.f);
    float var = s2 * (1.f/65536.f) - mu*mu;
    float a = gamma[ch] * rsqrtf(var + BN_EPS);
    bn_a[item*C128 + ch] = a;
    bn_c[item*C128 + ch] = beta[ch] - a*mu;
  }
}

// ---------------- final: BN2+ReLU, transpose [item][w][o][h] -> NCHW ----------------
__global__ __launch_bounds__(256) void k_final(
    const float* __restrict__ y_t, const float* __restrict__ bn_a,
    const float* __restrict__ bn_c, float* __restrict__ out)
{
  __shared__ float tile[64][65];
  int ch = blockIdx.z & 127, item = blockIdx.z >> 7;
  int w0 = blockIdx.x*64, h0 = blockIdx.y*64;
  int t = threadIdx.x;
  float a = bn_a[item*C128 + ch], c = bn_c[item*C128 + ch];
  int ww = t >> 2, hr = (t & 3)*16;
  const float* sp = y_t + (((size_t)item*IMGW + w0 + ww)*C128 + ch)*IMGH + h0 + hr;
  #pragma unroll
  for (int k = 0; k < 16; k += 4) {
    float4 v = *reinterpret_cast<const float4*>(sp + k);
    tile[hr+k+0][ww] = fmaxf(fmaf(a, v.x, c), 0.f);
    tile[hr+k+1][ww] = fmaxf(fmaf(a, v.y, c), 0.f);
    tile[hr+k+2][ww] = fmaxf(fmaf(a, v.z, c), 0.f);
    tile[hr+k+3][ww] = fmaxf(fmaf(a, v.w, c), 0.f);
  }
  __syncthreads();
  int hh = t >> 2, wr = (t & 3)*16;
  float* dp = out + (((size_t)item*C128 + ch)*IMGH + h0 + hh)*IMGW + w0 + wr;
  #pragma unroll
  for (int k = 0; k < 16; k += 4) {
    float4 v;
    v.x = tile[hh][wr+k]; v.y = tile[hh][wr+k+1];
    v.z = tile[hh][wr+k+2]; v.w = tile[hh][wr+k+3];
    *reinterpret_cast<float4*>(dp + k) = v;
  }
}

extern "C" void kernel_launch(void* const* d_in, const int* in_sizes, int n_in,
                              void* d_out, int out_size, void* d_ws, size_t ws_size,
                              hipStream_t stream) {
  const float* x        = (const float*)d_in[0];
  const float* seidel   = (const float*)d_in[1];
  const float* m1_w1    = (const float*)d_in[2];
  const float* m1_b1    = (const float*)d_in[3];
  const float* m1_w2    = (const float*)d_in[4];
  const float* m1_b2    = (const float*)d_in[5];
  const float* m2_w1    = (const float*)d_in[6];
  const float* m2_b1    = (const float*)d_in[7];
  const float* m2_w2    = (const float*)d_in[8];
  const float* m2_b2    = (const float*)d_in[9];
  const float* hyper_w  = (const float*)d_in[10];
  const float* hyper_b  = (const float*)d_in[11];
  const float* bn1_g    = (const float*)d_in[12];
  const float* bn1_b    = (const float*)d_in[13];
  const float* bn2_g    = (const float*)d_in[14];
  const float* bn2_b    = (const float*)d_in[15];

  char* ws = (char*)d_ws;
  // ws layout (bytes):
  //   e_all   [16*128]                @ 0         (8 KB)
  //   wbase   [2][2][8][3][3][128][128] @ 8192    (18,874,368)
  //   x_t     [2][256][128][256]      @ 18882560  (67,108,864)  (aliased as y2_t)
  //   y1_t    [2][256][128][256]      @ 85991424  (67,108,864)
  //   bn a/c  4*256 floats            @ 153100288 (4 KB)        total ~146 MB
  float* e_all = (float*)ws;
  float* wbase = (float*)(ws + 8192);
  float* x_t   = (float*)(ws + 8192 + 18874368);
  float* y1_t  = (float*)(ws + 8192 + 18874368 + 67108864);
  float* y2_t  = x_t;  // x_t is dead after conv1
  float* bnbuf = (float*)(ws + 8192 + 18874368 + 67108864 + 67108864);
  float* bn1_a = bnbuf,       *bn1_c = bnbuf + 256;
  float* bn2_a = bnbuf + 512, *bn2_c = bnbuf + 768;

  k_mlp<<<16, 128, 0, stream>>>(seidel, m1_w1, m1_b1, m1_w2, m1_b2,
                                m2_w1, m2_b1, m2_w2, m2_b2, e_all);
  k_hyper<<<HYPER_OUT/256, 256, 0, stream>>>(e_all, hyper_w, hyper_b, wbase);
  k_transpose<<<dim3(4, 4, NB*C128), 256, 0, stream>>>(x, x_t);

  k_conv<false><<<dim3(IMGW, 2, NB), 256, 0, stream>>>(x_t, wbase, nullptr, nullptr, y1_t);
  k_stats<<<NB*C128, 256, 0, stream>>>(y1_t, bn1_g, bn1_b, bn1_a, bn1_c);

  k_conv<true><<<dim3(IMGW, 2, NB), 256, 0, stream>>>(y1_t, wbase + (size_t)2*8*9*16384,
                                                      bn1_a, bn1_c, y2_t);
  k_stats<<<NB*C128, 256, 0, stream>>>(y2_t, bn2_g, bn2_b, bn2_a, bn2_c);
  k_final<<<dim3(4, 4, NB*C128), 256, 0, stream>>>(y2_t, bn2_a, bn2_c, (float*)d_out);
}

// Round 2
// 486.229 us; speedup vs baseline: 2.8590x; 2.8590x over previous
//
#include <hip/hip_runtime.h>

// DoubleConv: hypernet 3x3 radius-interp conv x2 + per-item BN+ReLU.
// Round 2: bf16 MFMA conv (16x16x32), dual-radius accumulate + epilogue lerp,
// fused BN-stats reduction in conv epilogue.

#define SD 6
#define HD 128
#define HYPER_OUT 294912
#define BN_EPS 1e-5f

typedef unsigned short ushort_t;
typedef __attribute__((ext_vector_type(8))) short bf16x8;
typedef __attribute__((ext_vector_type(4))) float f32x4;

__device__ inline ushort_t f2bf(float f) {
  union { float f; unsigned u; } v; v.f = f;
  unsigned r = v.u + 0x7fffu + ((v.u >> 16) & 1u);   // RNE
  return (ushort_t)(r >> 16);
}
__device__ inline float bf2f(ushort_t h) {
  union { unsigned u; float f; } v; v.u = ((unsigned)h) << 16; return v.f;
}
__device__ inline unsigned pack2(float a, float b) {
  return (unsigned)f2bf(a) | ((unsigned)f2bf(b) << 16);
}

// ---------------- e-MLPs: e_all[16][128], row = item*8 + conv*4 + n ----------------
__global__ __launch_bounds__(128) void k_mlp(
    const float* __restrict__ seidel,
    const float* __restrict__ m1_w1, const float* __restrict__ m1_b1,
    const float* __restrict__ m1_w2, const float* __restrict__ m1_b2,
    const float* __restrict__ m2_w1, const float* __restrict__ m2_b1,
    const float* __restrict__ m2_w2, const float* __restrict__ m2_b2,
    float* __restrict__ e_all)
{
  int b = blockIdx.x;                 // 16 blocks
  int item = b >> 3, conv = (b >> 2) & 1, n = b & 3;
  const float* w1 = conv ? m2_w1 : m1_w1;
  const float* b1 = conv ? m2_b1 : m1_b1;
  const float* w2 = conv ? m2_w2 : m1_w2;
  const float* b2 = conv ? m2_b2 : m1_b2;
  int t = threadIdx.x;                // 128
  __shared__ float e1[HD];
  float s = b1[n*HD + t];
  #pragma unroll
  for (int i = 0; i < SD; ++i) s = fmaf(seidel[item*SD + i], w1[(n*SD + i)*HD + t], s);
  e1[t] = fmaxf(s, 0.f);
  __syncthreads();
  float s2 = b2[n*HD + t];
  for (int i = 0; i < HD; ++i) s2 = fmaf(e1[i], w2[(n*HD + i)*HD + t], s2);
  e_all[b*HD + t] = fmaxf(s2, 0.f);
}

// ---------------- hyper GEMM -> bf16 weights [conv][item][r][ki][kj][o(128)][c(128)] --
__global__ __launch_bounds__(256) void k_hyper(
    const float* __restrict__ e_all, const float* __restrict__ hyper_w,
    const float* __restrict__ hyper_b, ushort_t* __restrict__ wb)
{
  __shared__ float es[16*HD];
  int t = threadIdx.x;
  for (int f = t; f < 16*HD; f += 256) es[f] = e_all[f];
  __syncthreads();
  int j = blockIdx.x*256 + t;         // 1152 blocks * 256 = 294912
  float val[16];
  #pragma unroll
  for (int r = 0; r < 16; ++r) val[r] = 0.f;
  for (int i = 0; i < HD; ++i) {
    float hw = hyper_w[(size_t)i*HYPER_OUT + j];
    #pragma unroll
    for (int r = 0; r < 16; ++r) val[r] = fmaf(es[r*HD + i], hw, val[r]);
  }
  float bias = hyper_b[j];
  int kj = j % 3; int tt = j / 3;
  int ki = tt % 3; tt /= 3;
  int nr = tt & 7; tt >>= 3;
  int v  = tt & 63; int u = tt >> 6;
  #pragma unroll
  for (int r = 0; r < 16; ++r) {
    int item = r >> 3, conv = (r >> 2) & 1, n = r & 3;
    int o = (n >> 1)*64 + u;          // out channel
    int c = (n & 1)*64 + v;           // in channel
    size_t off = (((((size_t)(conv*2 + item)*8 + nr)*3 + ki)*3 + kj)*128 + o)*128 + c;
    wb[off] = f2bf(val[r] + bias);
  }
}

// ---------------- transpose x: [item][c][h][w] f32 -> [item][w][h][c] bf16 ----------
__global__ __launch_bounds__(256) void k_transpose(
    const float* __restrict__ x, ushort_t* __restrict__ xt)
{
  __shared__ float tile[64][65];      // [c][w]
  int wt = blockIdx.x, ct = blockIdx.y;
  int h = blockIdx.z & 255, item = blockIdx.z >> 8;
  int t = threadIdx.x;
  {
    int cl = t >> 2, wk = (t & 3) << 4;
    const float* sp = x + (((size_t)item*128 + ct*64 + cl)*256 + h)*256 + wt*64 + wk;
    #pragma unroll
    for (int k = 0; k < 16; k += 4) {
      float4 v = *reinterpret_cast<const float4*>(sp + k);
      tile[cl][wk+k] = v.x; tile[cl][wk+k+1] = v.y;
      tile[cl][wk+k+2] = v.z; tile[cl][wk+k+3] = v.w;
    }
  }
  __syncthreads();
  {
    int wl = t >> 2, ck = (t & 3) << 4;
    ushort_t* dp = xt + (((size_t)item*256 + wt*64 + wl)*256 + h)*128 + ct*64 + ck;
    uint4 u0, u1;
    u0.x = pack2(tile[ck+0][wl],  tile[ck+1][wl]);
    u0.y = pack2(tile[ck+2][wl],  tile[ck+3][wl]);
    u0.z = pack2(tile[ck+4][wl],  tile[ck+5][wl]);
    u0.w = pack2(tile[ck+6][wl],  tile[ck+7][wl]);
    u1.x = pack2(tile[ck+8][wl],  tile[ck+9][wl]);
    u1.y = pack2(tile[ck+10][wl], tile[ck+11][wl]);
    u1.z = pack2(tile[ck+12][wl], tile[ck+13][wl]);
    u1.w = pack2(tile[ck+14][wl], tile[ck+15][wl]);
    *reinterpret_cast<uint4*>(dp)     = u0;
    *reinterpret_cast<uint4*>(dp + 8) = u1;
  }
}

// ---------------- MFMA conv ----------------
// src [item][w][h][c] bf16 ; wb per-conv base [item][r][ki][kj][o][c] bf16
// dst [item][w][h][o] bf16 (pre-BN) ; ps/p2 per-block BN partial sums [1024][128]
// grid (256 w-swz, 2 hb, 2 item), 256 threads = 4 waves (2 o-halves x 2 h-halves).
template<bool BN_IN>
__global__ __launch_bounds__(256, 2) void k_conv(
    const ushort_t* __restrict__ src, const ushort_t* __restrict__ wb,
    const float* __restrict__ bn_a, const float* __restrict__ bn_c,
    ushort_t* __restrict__ dst, float* __restrict__ ps, float* __restrict__ p2)
{
  __shared__ __align__(16) ushort_t As[130*136];   // [h(130)][c pad 136]
  __shared__ __align__(16) ushort_t Bs[2*128*72];  // [radius][o(128)][c64 pad 72]
  __shared__ float sbn[256];
  int bx = blockIdx.x;
  int w = ((bx & 7) << 5) | (bx >> 3);             // XCD-contiguous w ranges
  int hb = blockIdx.y, item = blockIdx.z;
  int t = threadIdx.x;
  int lane = t & 63, wid = t >> 6;
  int l15 = lane & 15, g = lane >> 4;
  int wm = wid >> 1, wn = wid & 1;

  float pos = fminf(fmaxf((w + 0.5f)*0.03125f - 0.5f, 0.f), 7.f);
  int i0 = (int)pos; float fr = pos - (float)i0; int i1 = min(i0 + 1, 7);

  if constexpr (BN_IN)
    sbn[t] = (t < 128) ? bn_a[item*128 + t] : bn_c[item*128 + (t - 128)];

  const ushort_t* wbi = wb + (size_t)item*8*9*16384;

  f32x4 acc[2][4][4];
  #pragma unroll
  for (int r = 0; r < 2; ++r)
    #pragma unroll
    for (int a = 0; a < 4; ++a)
      #pragma unroll
      for (int b = 0; b < 4; ++b)
        acc[r][a][b] = (f32x4){0.f, 0.f, 0.f, 0.f};

  for (int kj = 0; kj < 3; ++kj) {
    int wc = w + kj - 1;
    bool valid = (wc >= 0) && (wc < 256);
    const ushort_t* sb = src + ((size_t)item*256 + (valid ? wc : 0))*32768;
    __syncthreads();                               // As readers (prev kj) done
    for (int f = t; f < 130*16; f += 256) {
      int row = f >> 4, ck = (f & 15) << 3;
      uint4 v = make_uint4(0u, 0u, 0u, 0u);
      if (valid) {
        int hg = (hb*128 + row - 1) & 255;         // circular pad in H
        v = *reinterpret_cast<const uint4*>(sb + ((size_t)hg << 7) + ck);
        if constexpr (BN_IN) {
          ushort_t* pv = reinterpret_cast<ushort_t*>(&v);
          #pragma unroll
          for (int jj = 0; jj < 8; ++jj) {
            float xv = bf2f(pv[jj]);
            xv = fmaxf(fmaf(sbn[ck + jj], xv, sbn[128 + ck + jj]), 0.f);
            pv[jj] = f2bf(xv);
          }
        }
      }
      *reinterpret_cast<uint4*>(&As[row*136 + ck]) = v;
    }
    for (int ki = 0; ki < 3; ++ki) {
      for (int ch = 0; ch < 2; ++ch) {
        __syncthreads();                           // Bs readers done / As ready
        const ushort_t* w0p = wbi + ((size_t)i0*9 + ki*3 + kj)*16384 + ch*64;
        const ushort_t* w1p = wbi + ((size_t)i1*9 + ki*3 + kj)*16384 + ch*64;
        for (int f = t; f < 2048; f += 256) {
          int rr = f >> 10, o = (f >> 3) & 127, ck = (f & 7) << 3;
          const ushort_t* sp = (rr ? w1p : w0p) + o*128 + ck;
          *reinterpret_cast<uint4*>(&Bs[((rr << 7) + o)*72 + ck]) =
              *reinterpret_cast<const uint4*>(sp);
        }
        __syncthreads();
        #pragma unroll
        for (int ks = 0; ks < 2; ++ks) {
          bf16x8 bfr[4];
          #pragma unroll
          for (int nf = 0; nf < 4; ++nf)
            bfr[nf] = *reinterpret_cast<const bf16x8*>(
                &As[(wn*64 + nf*16 + l15 + ki)*136 + ch*64 + ks*32 + (g << 3)]);
          #pragma unroll
          for (int r = 0; r < 2; ++r) {
            #pragma unroll
            for (int mf = 0; mf < 4; ++mf) {
              bf16x8 af = *reinterpret_cast<const bf16x8*>(
                  &Bs[((r << 7) + wm*64 + mf*16 + l15)*72 + ks*32 + (g << 3)]);
              #pragma unroll
              for (int nf = 0; nf < 4; ++nf)
                acc[r][mf][nf] = __builtin_amdgcn_mfma_f32_16x16x32_bf16(
                    af, bfr[nf], acc[r][mf][nf], 0, 0, 0);
            }
          }
        }
      }
    }
  }

  // epilogue: lerp, store bf16 [h][o], accumulate BN partials
  float w0f = 1.f - fr, w1f = fr;
  ushort_t* yb = dst + (((size_t)item*256 + w)*256 + hb*128)*128;
  float ssum[4][4], s2sum[4][4];
  #pragma unroll
  for (int a = 0; a < 4; ++a)
    #pragma unroll
    for (int b = 0; b < 4; ++b) { ssum[a][b] = 0.f; s2sum[a][b] = 0.f; }
  #pragma unroll
  for (int mf = 0; mf < 4; ++mf) {
    #pragma unroll
    for (int nf = 0; nf < 4; ++nf) {
      float v[4];
      #pragma unroll
      for (int r4 = 0; r4 < 4; ++r4) {
        v[r4] = fmaf(w1f, acc[1][mf][nf][r4], w0f*acc[0][mf][nf][r4]);
        ssum[mf][r4] += v[r4];
        s2sum[mf][r4] = fmaf(v[r4], v[r4], s2sum[mf][r4]);
      }
      int h  = wn*64 + nf*16 + l15;
      int o0 = wm*64 + mf*16 + (g << 2);
      uint2 u; u.x = pack2(v[0], v[1]); u.y = pack2(v[2], v[3]);
      *reinterpret_cast<uint2*>(yb + (size_t)h*128 + o0) = u;
    }
  }
  #pragma unroll
  for (int mf = 0; mf < 4; ++mf)
    #pragma unroll
    for (int r4 = 0; r4 < 4; ++r4)
      #pragma unroll
      for (int m = 1; m < 16; m <<= 1) {
        ssum[mf][r4]  += __shfl_xor(ssum[mf][r4], m);
        s2sum[mf][r4] += __shfl_xor(s2sum[mf][r4], m);
      }
  __syncthreads();                                 // reuse As as reduction scratch
  float* redS  = reinterpret_cast<float*>(As);     // [4 wave][64 o-local]
  float* redS2 = redS + 256;
  if (l15 == 0) {
    #pragma unroll
    for (int mf = 0; mf < 4; ++mf)
      #pragma unroll
      for (int r4 = 0; r4 < 4; ++r4) {
        int ol = mf*16 + (g << 2) + r4;
        redS [wid*64 + ol] = ssum[mf][r4];
        redS2[wid*64 + ol] = s2sum[mf][r4];
      }
  }
  __syncthreads();
  if (t < 128) {
    int o = t, wmS = o >> 6, ol = o & 63;
    float S  = redS [(wmS*2)*64 + ol] + redS [(wmS*2+1)*64 + ol];
    float S2 = redS2[(wmS*2)*64 + ol] + redS2[(wmS*2+1)*64 + ol];
    size_t bi = ((size_t)item*256 + w)*2 + hb;
    ps[bi*128 + o] = S;
    p2[bi*128 + o] = S2;
  }
}

// ---------------- reduce partials -> BN affine (a,c) ----------------
__global__ __launch_bounds__(128) void k_bnapply(
    const float* __restrict__ ps, const float* __restrict__ p2,
    const float* __restrict__ gamma, const float* __restrict__ beta,
    float* __restrict__ bn_a, float* __restrict__ bn_c)
{
  int item = blockIdx.x, o = threadIdx.x;
  float s = 0.f, s2 = 0.f;
  for (int i = 0; i < 512; ++i) {
    size_t bi = (size_t)(item*512 + i)*128 + o;
    s += ps[bi]; s2 += p2[bi];
  }
  float mu  = s  * (1.f/65536.f);
  float var = s2 * (1.f/65536.f) - mu*mu;
  float a = gamma[o] * rsqrtf(var + BN_EPS);
  bn_a[item*128 + o] = a;
  bn_c[item*128 + o] = beta[o] - a*mu;
}

// ---------------- final: BN2+ReLU + transpose [item][w][h][o] bf16 -> NCHW f32 ------
__global__ __launch_bounds__(256) void k_final(
    const ushort_t* __restrict__ y, const float* __restrict__ bn_a,
    const float* __restrict__ bn_c, float* __restrict__ out)
{
  __shared__ float tile[64][65];      // [w][o]
  int wt = blockIdx.x, ot = blockIdx.y;
  int h = blockIdx.z & 255, item = blockIdx.z >> 8;
  int t = threadIdx.x;
  {
    int wl = t >> 2, ck = (t & 3) << 4;
    const ushort_t* sp = y + (((size_t)item*256 + wt*64 + wl)*256 + h)*128 + ot*64 + ck;
    uint4 a = *reinterpret_cast<const uint4*>(sp);
    uint4 b = *reinterpret_cast<const uint4*>(sp + 8);
    const ushort_t* pa = reinterpret_cast<const ushort_t*>(&a);
    const ushort_t* pb = reinterpret_cast<const ushort_t*>(&b);
    #pragma unroll
    for (int k = 0; k < 8; ++k) {
      int o = ot*64 + ck + k;
      tile[wl][ck + k] = fmaxf(fmaf(bn_a[item*128 + o], bf2f(pa[k]), bn_c[item*128 + o]), 0.f);
    }
    #pragma unroll
    for (int k = 0; k < 8; ++k) {
      int o = ot*64 + ck + 8 + k;
      tile[wl][ck + 8 + k] = fmaxf(fmaf(bn_a[item*128 + o], bf2f(pb[k]), bn_c[item*128 + o]), 0.f);
    }
  }
  __syncthreads();
  {
    int ol = t >> 2, wk = (t & 3) << 4;
    float* dp = out + (((size_t)item*128 + ot*64 + ol)*256 + h)*256 + wt*64 + wk;
    #pragma unroll
    for (int k = 0; k < 16; k += 4) {
      float4 v;
      v.x = tile[wk+k][ol];   v.y = tile[wk+k+1][ol];
      v.z = tile[wk+k+2][ol]; v.w = tile[wk+k+3][ol];
      *reinterpret_cast<float4*>(dp + k) = v;
    }
  }
}

extern "C" void kernel_launch(void* const* d_in, const int* in_sizes, int n_in,
                              void* d_out, int out_size, void* d_ws, size_t ws_size,
                              hipStream_t stream) {
  const float* x       = (const float*)d_in[0];
  const float* seidel  = (const float*)d_in[1];
  const float* m1_w1   = (const float*)d_in[2];
  const float* m1_b1   = (const float*)d_in[3];
  const float* m1_w2   = (const float*)d_in[4];
  const float* m1_b2   = (const float*)d_in[5];
  const float* m2_w1   = (const float*)d_in[6];
  const float* m2_b1   = (const float*)d_in[7];
  const float* m2_w2   = (const float*)d_in[8];
  const float* m2_b2   = (const float*)d_in[9];
  const float* hyper_w = (const float*)d_in[10];
  const float* hyper_b = (const float*)d_in[11];
  const float* bn1_g   = (const float*)d_in[12];
  const float* bn1_b   = (const float*)d_in[13];
  const float* bn2_g   = (const float*)d_in[14];
  const float* bn2_b   = (const float*)d_in[15];

  char* ws = (char*)d_ws;
  // ws layout (bytes):
  float*    e_all = (float*)ws;                                   // 8192
  ushort_t* wb    = (ushort_t*)(ws + 8192);                       // 9,437,184
  ushort_t* xt    = (ushort_t*)(ws + 8192 + 9437184);             // 33,554,432
  ushort_t* y1    = (ushort_t*)(ws + 8192 + 9437184 + 33554432);  // 33,554,432
  ushort_t* y2    = (ushort_t*)(ws + 8192 + 9437184 + 67108864);  // 33,554,432
  float*    ps    = (float*)(ws + 8192 + 9437184 + 100663296);    // 524,288
  float*    p2    = (float*)(ws + 8192 + 9437184 + 101187584);    // 524,288
  float*    bnb   = (float*)(ws + 8192 + 9437184 + 101711872);    // 4 KB
  float* bn1_a = bnb,        *bn1_c = bnb + 256;
  float* bn2_a = bnb + 512,  *bn2_c = bnb + 768;

  k_mlp<<<16, 128, 0, stream>>>(seidel, m1_w1, m1_b1, m1_w2, m1_b2,
                                m2_w1, m2_b1, m2_w2, m2_b2, e_all);
  k_hyper<<<HYPER_OUT/256, 256, 0, stream>>>(e_all, hyper_w, hyper_b, wb);
  k_transpose<<<dim3(4, 2, 512), 256, 0, stream>>>(x, xt);

  k_conv<false><<<dim3(256, 2, 2), 256, 0, stream>>>(xt, wb, nullptr, nullptr, y1, ps, p2);
  k_bnapply<<<2, 128, 0, stream>>>(ps, p2, bn1_g, bn1_b, bn1_a, bn1_c);

  k_conv<true><<<dim3(256, 2, 2), 256, 0, stream>>>(y1, wb + (size_t)2*2*8*9*16384/2*0 + 2359296,
                                                    bn1_a, bn1_c, y2, ps, p2);
  k_bnapply<<<2, 128, 0, stream>>>(ps, p2, bn2_g, bn2_b, bn2_a, bn2_c);
  k_final<<<dim3(4, 2, 512), 256, 0, stream>>>(y2, bn2_a, bn2_c, (float*)d_out);
}

// Round 3
// 325.463 us; speedup vs baseline: 4.2712x; 1.4940x over previous
//
#include <hip/hip_runtime.h>

// DoubleConv: hypernet 3x3 radius-interp conv x2 + per-item BN+ReLU.
// Round 3: single-radius lerp-at-stage, XOR-swizzled LDS (no pad), 3 blocks/CU,
// coalesced hypernet writes + repack kernel.

#define SD 6
#define HD 128
#define HYPER_OUT 294912
#define BN_EPS 1e-5f

typedef unsigned short ushort_t;
typedef __attribute__((ext_vector_type(8))) short bf16x8;
typedef __attribute__((ext_vector_type(4))) float f32x4;

__device__ inline ushort_t f2bf(float f) {
  union { float f; unsigned u; } v; v.f = f;
  unsigned r = v.u + 0x7fffu + ((v.u >> 16) & 1u);   // RNE
  return (ushort_t)(r >> 16);
}
__device__ inline float bf2f(ushort_t h) {
  union { unsigned u; float f; } v; v.u = ((unsigned)h) << 16; return v.f;
}
__device__ inline unsigned pack2(float a, float b) {
  return (unsigned)f2bf(a) | ((unsigned)f2bf(b) << 16);
}

// LDS element offsets with XOR bank swizzle (16B-unit index low-3-bits ^= row&7)
__device__ inline int as_off(int row, int cu) {    // As[130 rows][16 units of 8]
  return row*128 + ((cu ^ (row & 7)) << 3);
}
__device__ inline int bs_off(int o, int cu) {      // Bs[128 rows][8 units of 8]
  return o*64 + ((cu ^ (o & 7)) << 3);
}

// ---------------- e-MLPs: e_all[16][128], row = item*8 + conv*4 + n ----------------
__global__ __launch_bounds__(128) void k_mlp(
    const float* __restrict__ seidel,
    const float* __restrict__ m1_w1, const float* __restrict__ m1_b1,
    const float* __restrict__ m1_w2, const float* __restrict__ m1_b2,
    const float* __restrict__ m2_w1, const float* __restrict__ m2_b1,
    const float* __restrict__ m2_w2, const float* __restrict__ m2_b2,
    float* __restrict__ e_all)
{
  int b = blockIdx.x;                 // 16 blocks
  int item = b >> 3, conv = (b >> 2) & 1, n = b & 3;
  const float* w1 = conv ? m2_w1 : m1_w1;
  const float* b1 = conv ? m2_b1 : m1_b1;
  const float* w2 = conv ? m2_w2 : m1_w2;
  const float* b2 = conv ? m2_b2 : m1_b2;
  int t = threadIdx.x;                // 128
  __shared__ float e1[HD];
  float s = b1[n*HD + t];
  #pragma unroll
  for (int i = 0; i < SD; ++i) s = fmaf(seidel[item*SD + i], w1[(n*SD + i)*HD + t], s);
  e1[t] = fmaxf(s, 0.f);
  __syncthreads();
  float s2 = b2[n*HD + t];
  for (int i = 0; i < HD; ++i) s2 = fmaf(e1[i], w2[(n*HD + i)*HD + t], s2);
  e_all[b*HD + t] = fmaxf(s2, 0.f);
}

// ---------------- hyper GEMM -> wb_lin[j][16] bf16 (fully coalesced writes) --------
__global__ __launch_bounds__(256) void k_hyper(
    const float* __restrict__ e_all, const float* __restrict__ hyper_w,
    const float* __restrict__ hyper_b, ushort_t* __restrict__ wb_lin)
{
  __shared__ float es[16*HD];
  int t = threadIdx.x;
  for (int f = t; f < 16*HD; f += 256) es[f] = e_all[f];
  __syncthreads();
  int j = blockIdx.x*256 + t;         // 1152 blocks * 256 = 294912
  float val[16];
  #pragma unroll
  for (int r = 0; r < 16; ++r) val[r] = 0.f;
  for (int i = 0; i < HD; ++i) {
    float hw = hyper_w[(size_t)i*HYPER_OUT + j];
    #pragma unroll
    for (int r = 0; r < 16; ++r) val[r] = fmaf(es[r*HD + i], hw, val[r]);
  }
  float bias = hyper_b[j];
  uint4 u0, u1;
  u0.x = pack2(val[0]+bias,  val[1]+bias);
  u0.y = pack2(val[2]+bias,  val[3]+bias);
  u0.z = pack2(val[4]+bias,  val[5]+bias);
  u0.w = pack2(val[6]+bias,  val[7]+bias);
  u1.x = pack2(val[8]+bias,  val[9]+bias);
  u1.y = pack2(val[10]+bias, val[11]+bias);
  u1.z = pack2(val[12]+bias, val[13]+bias);
  u1.w = pack2(val[14]+bias, val[15]+bias);
  *reinterpret_cast<uint4*>(wb_lin + (size_t)j*16)     = u0;
  *reinterpret_cast<uint4*>(wb_lin + (size_t)j*16 + 8) = u1;
}

// ---------------- repack wb_lin[j][16] -> wb[(conv*2+item)][nr][ki][kj][o][c] ------
__global__ __launch_bounds__(256) void k_repack(
    const ushort_t* __restrict__ wb_lin, ushort_t* __restrict__ wb)
{
  __shared__ ushort_t lds[16][256];
  int chunk = blockIdx.x;             // 0..15 (u-groups of 4)
  int tap   = blockIdx.y;             // 0..71
  int nr = tap / 9, kk = tap % 9;
  int t = threadIdx.x;
  int uv = chunk*256 + t;             // u = uv>>6, v = uv&63
  size_t j = (size_t)uv*72 + nr*9 + kk;
  uint4 q0 = *reinterpret_cast<const uint4*>(wb_lin + j*16);
  uint4 q1 = *reinterpret_cast<const uint4*>(wb_lin + j*16 + 8);
  const ushort_t* pr0 = reinterpret_cast<const ushort_t*>(&q0);
  const ushort_t* pr1 = reinterpret_cast<const ushort_t*>(&q1);
  #pragma unroll
  for (int r = 0; r < 8; ++r) lds[r][t]     = pr0[r];
  #pragma unroll
  for (int r = 0; r < 8; ++r) lds[r + 8][t] = pr1[r];
  __syncthreads();
  #pragma unroll
  for (int it = 0; it < 2; ++it) {
    int idx = it*256 + t;             // 512 row-segments
    int row = idx >> 3, seg = idx & 7;
    int p = row >> 2, ul = row & 3;
    int item = p >> 3, conv = (p >> 2) & 1, n = p & 3;
    int o = (n >> 1)*64 + chunk*4 + ul;
    int c = (n & 1)*64 + seg*8;
    uint4 v = *reinterpret_cast<const uint4*>(&lds[p][ul*64 + seg*8]);
    size_t off = ((((size_t)(conv*2 + item)*8 + nr)*9 + kk)*128 + o)*128 + c;
    *reinterpret_cast<uint4*>(wb + off) = v;
  }
}

// ---------------- transpose x: [item][c][h][w] f32 -> [item][w][h][c] bf16 ----------
__global__ __launch_bounds__(256) void k_transpose(
    const float* __restrict__ x, ushort_t* __restrict__ xt)
{
  __shared__ float tile[64][65];      // [c][w]
  int wt = blockIdx.x, ct = blockIdx.y;
  int h = blockIdx.z & 255, item = blockIdx.z >> 8;
  int t = threadIdx.x;
  {
    int cl = t >> 2, wk = (t & 3) << 4;
    const float* sp = x + (((size_t)item*128 + ct*64 + cl)*256 + h)*256 + wt*64 + wk;
    #pragma unroll
    for (int k = 0; k < 16; k += 4) {
      float4 v = *reinterpret_cast<const float4*>(sp + k);
      tile[cl][wk+k] = v.x; tile[cl][wk+k+1] = v.y;
      tile[cl][wk+k+2] = v.z; tile[cl][wk+k+3] = v.w;
    }
  }
  __syncthreads();
  {
    int wl = t >> 2, ck = (t & 3) << 4;
    ushort_t* dp = xt + (((size_t)item*256 + wt*64 + wl)*256 + h)*128 + ct*64 + ck;
    uint4 u0, u1;
    u0.x = pack2(tile[ck+0][wl],  tile[ck+1][wl]);
    u0.y = pack2(tile[ck+2][wl],  tile[ck+3][wl]);
    u0.z = pack2(tile[ck+4][wl],  tile[ck+5][wl]);
    u0.w = pack2(tile[ck+6][wl],  tile[ck+7][wl]);
    u1.x = pack2(tile[ck+8][wl],  tile[ck+9][wl]);
    u1.y = pack2(tile[ck+10][wl], tile[ck+11][wl]);
    u1.z = pack2(tile[ck+12][wl], tile[ck+13][wl]);
    u1.w = pack2(tile[ck+14][wl], tile[ck+15][wl]);
    *reinterpret_cast<uint4*>(dp)     = u0;
    *reinterpret_cast<uint4*>(dp + 8) = u1;
  }
}

// ---------------- MFMA conv (single radius, lerp at Bs staging) ----------------
// src [item][w][h][c] bf16 ; wb per-conv base [item][nr][ki][kj][o][c] bf16
// dst [item][w][h][o] bf16 (pre-BN) ; ps/p2 per-block BN partials [1024][128]
// grid (256 w-swz, 2 hb, 2 item), 256 threads = 4 waves (2 o x 2 h).
template<bool BN_IN>
__global__ __launch_bounds__(256, 3) void k_conv(
    const ushort_t* __restrict__ src, const ushort_t* __restrict__ wb,
    const float* __restrict__ bn_a, const float* __restrict__ bn_c,
    ushort_t* __restrict__ dst, float* __restrict__ ps, float* __restrict__ p2)
{
  __shared__ __align__(16) ushort_t As[130*128];   // 33,280 B  (swizzled)
  __shared__ __align__(16) ushort_t Bs[128*64];    // 16,384 B  (swizzled)
  __shared__ float sbn[256];
  int bx = blockIdx.x;
  int w = ((bx & 7) << 5) | (bx >> 3);             // XCD-contiguous w ranges
  int hb = blockIdx.y, item = blockIdx.z;
  int t = threadIdx.x;
  int lane = t & 63, wid = t >> 6;
  int l15 = lane & 15, g = lane >> 4;
  int wm = wid >> 1, wn = wid & 1;

  float pos = fminf(fmaxf((w + 0.5f)*0.03125f - 0.5f, 0.f), 7.f);
  int i0 = (int)pos; float fr = pos - (float)i0; int i1 = min(i0 + 1, 7);

  if constexpr (BN_IN)
    sbn[t] = (t < 128) ? bn_a[item*128 + t] : bn_c[item*128 + (t - 128)];

  const ushort_t* wbi = wb + (size_t)item*1179648;  // 8*9*16384

  f32x4 acc[4][4];
  #pragma unroll
  for (int a = 0; a < 4; ++a)
    #pragma unroll
    for (int b = 0; b < 4; ++b)
      acc[a][b] = (f32x4){0.f, 0.f, 0.f, 0.f};

  for (int s = 0; s < 18; ++s) {                   // s = kj*6 + ki*2 + ch
    int kj = (s >= 12) ? 2 : (s >= 6) ? 1 : 0;
    int r6 = s - kj*6;
    int ki = r6 >> 1, ch = r6 & 1;

    if (r6 == 0) {
      __syncthreads();                             // prev-kj MFMA done (As free; sbn visible)
      int wc = w + kj - 1;
      bool valid = (wc >= 0) && (wc < 256);
      const ushort_t* sb = src + ((size_t)item*256 + (valid ? wc : 0))*32768;
      for (int f = t; f < 2080; f += 256) {        // 130 rows x 16 units
        int row = f >> 4, cu = f & 15;
        uint4 v = make_uint4(0u, 0u, 0u, 0u);
        if (valid) {
          int hg = (hb*128 + row - 1) & 255;       // circular pad in H
          v = *reinterpret_cast<const uint4*>(sb + ((size_t)hg << 7) + (cu << 3));
          if constexpr (BN_IN) {
            ushort_t* pv = reinterpret_cast<ushort_t*>(&v);
            int c0 = cu << 3;
            #pragma unroll
            for (int jj = 0; jj < 8; ++jj) {
              float xv = bf2f(pv[jj]);
              xv = fmaxf(fmaf(sbn[c0 + jj], xv, sbn[128 + c0 + jj]), 0.f);
              pv[jj] = f2bf(xv);
            }
          }
        }
        *reinterpret_cast<uint4*>(&As[as_off(row, cu)]) = v;
      }
    }
    __syncthreads();                               // As visible / Bs free
    {
      const ushort_t* w0p = wbi + ((size_t)i0*9 + ki*3 + kj)*16384 + ch*64;
      const ushort_t* w1p = wbi + ((size_t)i1*9 + ki*3 + kj)*16384 + ch*64;
      #pragma unroll
      for (int jv = 0; jv < 4; ++jv) {
        int f = t + jv*256;                        // 1024 units
        int o = f >> 3, cu = f & 7;
        uint4 a = *reinterpret_cast<const uint4*>(w0p + o*128 + (cu << 3));
        uint4 b = *reinterpret_cast<const uint4*>(w1p + o*128 + (cu << 3));
        const ushort_t* pa = reinterpret_cast<const ushort_t*>(&a);
        const ushort_t* pb = reinterpret_cast<const ushort_t*>(&b);
        uint4 o4; ushort_t* po = reinterpret_cast<ushort_t*>(&o4);
        #pragma unroll
        for (int jj = 0; jj < 8; ++jj) {
          float av = bf2f(pa[jj]);
          po[jj] = f2bf(fmaf(fr, bf2f(pb[jj]) - av, av));
        }
        *reinterpret_cast<uint4*>(&Bs[bs_off(o, cu)]) = o4;
      }
    }
    __syncthreads();                               // Bs ready
    #pragma unroll
    for (int ks = 0; ks < 2; ++ks) {
      bf16x8 bfr[4];
      #pragma unroll
      for (int nf = 0; nf < 4; ++nf)
        bfr[nf] = *reinterpret_cast<const bf16x8*>(
            &As[as_off(wn*64 + nf*16 + l15 + ki, ch*8 + ks*4 + g)]);
      #pragma unroll
      for (int mf = 0; mf < 4; ++mf) {
        bf16x8 af = *reinterpret_cast<const bf16x8*>(
            &Bs[bs_off(wm*64 + mf*16 + l15, ks*4 + g)]);
        #pragma unroll
        for (int nf = 0; nf < 4; ++nf)
          acc[mf][nf] = __builtin_amdgcn_mfma_f32_16x16x32_bf16(
              af, bfr[nf], acc[mf][nf], 0, 0, 0);
      }
    }
  }

  // epilogue: store bf16 [h][o], accumulate BN partials
  ushort_t* yb = dst + (((size_t)item*256 + w)*256 + hb*128)*128;
  float ssum[4][4], s2sum[4][4];
  #pragma unroll
  for (int a = 0; a < 4; ++a)
    #pragma unroll
    for (int b = 0; b < 4; ++b) { ssum[a][b] = 0.f; s2sum[a][b] = 0.f; }
  #pragma unroll
  for (int mf = 0; mf < 4; ++mf) {
    #pragma unroll
    for (int nf = 0; nf < 4; ++nf) {
      float v[4];
      #pragma unroll
      for (int r4 = 0; r4 < 4; ++r4) {
        v[r4] = acc[mf][nf][r4];
        ssum[mf][r4] += v[r4];
        s2sum[mf][r4] = fmaf(v[r4], v[r4], s2sum[mf][r4]);
      }
      int h  = wn*64 + nf*16 + l15;
      int o0 = wm*64 + mf*16 + (g << 2);
      uint2 u; u.x = pack2(v[0], v[1]); u.y = pack2(v[2], v[3]);
      *reinterpret_cast<uint2*>(yb + (size_t)h*128 + o0) = u;
    }
  }
  #pragma unroll
  for (int mf = 0; mf < 4; ++mf)
    #pragma unroll
    for (int r4 = 0; r4 < 4; ++r4)
      #pragma unroll
      for (int m = 1; m < 16; m <<= 1) {
        ssum[mf][r4]  += __shfl_xor(ssum[mf][r4], m);
        s2sum[mf][r4] += __shfl_xor(s2sum[mf][r4], m);
      }
  __syncthreads();                                 // reuse As as reduction scratch
  float* redS  = reinterpret_cast<float*>(As);     // [4 wave][64 o-local]
  float* redS2 = redS + 256;
  if (l15 == 0) {
    #pragma unroll
    for (int mf = 0; mf < 4; ++mf)
      #pragma unroll
      for (int r4 = 0; r4 < 4; ++r4) {
        int ol = mf*16 + (g << 2) + r4;
        redS [wid*64 + ol] = ssum[mf][r4];
        redS2[wid*64 + ol] = s2sum[mf][r4];
      }
  }
  __syncthreads();
  if (t < 128) {
    int o = t, wmS = o >> 6, ol = o & 63;
    float S  = redS [(wmS*2)*64 + ol] + redS [(wmS*2+1)*64 + ol];
    float S2 = redS2[(wmS*2)*64 + ol] + redS2[(wmS*2+1)*64 + ol];
    size_t bi = ((size_t)item*256 + w)*2 + hb;
    ps[bi*128 + o] = S;
    p2[bi*128 + o] = S2;
  }
}

// ---------------- reduce partials -> BN affine (a,c) ----------------
__global__ __launch_bounds__(128) void k_bnapply(
    const float* __restrict__ ps, const float* __restrict__ p2,
    const float* __restrict__ gamma, const float* __restrict__ beta,
    float* __restrict__ bn_a, float* __restrict__ bn_c)
{
  int item = blockIdx.x, o = threadIdx.x;
  float s = 0.f, s2 = 0.f;
  for (int i = 0; i < 512; ++i) {
    size_t bi = (size_t)(item*512 + i)*128 + o;
    s += ps[bi]; s2 += p2[bi];
  }
  float mu  = s  * (1.f/65536.f);
  float var = s2 * (1.f/65536.f) - mu*mu;
  float a = gamma[o] * rsqrtf(var + BN_EPS);
  bn_a[item*128 + o] = a;
  bn_c[item*128 + o] = beta[o] - a*mu;
}

// ---------------- final: BN2+ReLU + transpose [item][w][h][o] bf16 -> NCHW f32 ------
__global__ __launch_bounds__(256) void k_final(
    const ushort_t* __restrict__ y, const float* __restrict__ bn_a,
    const float* __restrict__ bn_c, float* __restrict__ out)
{
  __shared__ float tile[64][65];      // [w][o]
  int wt = blockIdx.x, ot = blockIdx.y;
  int h = blockIdx.z & 255, item = blockIdx.z >> 8;
  int t = threadIdx.x;
  {
    int wl = t >> 2, ck = (t & 3) << 4;
    const ushort_t* sp = y + (((size_t)item*256 + wt*64 + wl)*256 + h)*128 + ot*64 + ck;
    uint4 a = *reinterpret_cast<const uint4*>(sp);
    uint4 b = *reinterpret_cast<const uint4*>(sp + 8);
    const ushort_t* pa = reinterpret_cast<const ushort_t*>(&a);
    const ushort_t* pb = reinterpret_cast<const ushort_t*>(&b);
    #pragma unroll
    for (int k = 0; k < 8; ++k) {
      int o = ot*64 + ck + k;
      tile[wl][ck + k] = fmaxf(fmaf(bn_a[item*128 + o], bf2f(pa[k]), bn_c[item*128 + o]), 0.f);
    }
    #pragma unroll
    for (int k = 0; k < 8; ++k) {
      int o = ot*64 + ck + 8 + k;
      tile[wl][ck + 8 + k] = fmaxf(fmaf(bn_a[item*128 + o], bf2f(pb[k]), bn_c[item*128 + o]), 0.f);
    }
  }
  __syncthreads();
  {
    int ol = t >> 2, wk = (t & 3) << 4;
    float* dp = out + (((size_t)item*128 + ot*64 + ol)*256 + h)*256 + wt*64 + wk;
    #pragma unroll
    for (int k = 0; k < 16; k += 4) {
      float4 v;
      v.x = tile[wk+k][ol];   v.y = tile[wk+k+1][ol];
      v.z = tile[wk+k+2][ol]; v.w = tile[wk+k+3][ol];
      *reinterpret_cast<float4*>(dp + k) = v;
    }
  }
}

extern "C" void kernel_launch(void* const* d_in, const int* in_sizes, int n_in,
                              void* d_out, int out_size, void* d_ws, size_t ws_size,
                              hipStream_t stream) {
  const float* x       = (const float*)d_in[0];
  const float* seidel  = (const float*)d_in[1];
  const float* m1_w1   = (const float*)d_in[2];
  const float* m1_b1   = (const float*)d_in[3];
  const float* m1_w2   = (const float*)d_in[4];
  const float* m1_b2   = (const float*)d_in[5];
  const float* m2_w1   = (const float*)d_in[6];
  const float* m2_b1   = (const float*)d_in[7];
  const float* m2_w2   = (const float*)d_in[8];
  const float* m2_b2   = (const float*)d_in[9];
  const float* hyper_w = (const float*)d_in[10];
  const float* hyper_b = (const float*)d_in[11];
  const float* bn1_g   = (const float*)d_in[12];
  const float* bn1_b   = (const float*)d_in[13];
  const float* bn2_g   = (const float*)d_in[14];
  const float* bn2_b   = (const float*)d_in[15];

  char* ws = (char*)d_ws;
  float*    e_all  = (float*)ws;                                    // 8,192
  ushort_t* wb_lin = (ushort_t*)(ws + 8192);                        // 9,437,184
  ushort_t* wb     = (ushort_t*)(ws + 9445376);                     // 9,437,184
  ushort_t* xt     = (ushort_t*)(ws + 18882560);                    // 33,554,432
  ushort_t* y1     = (ushort_t*)(ws + 52436992);                    // 33,554,432
  ushort_t* y2     = (ushort_t*)(ws + 85991424);                    // 33,554,432
  float*    ps     = (float*)(ws + 119545856);                      // 524,288
  float*    p2     = (float*)(ws + 120070144);                      // 524,288
  float*    bnb    = (float*)(ws + 120594432);                      // 4 KB
  float* bn1_a = bnb,        *bn1_c = bnb + 256;
  float* bn2_a = bnb + 512,  *bn2_c = bnb + 768;

  k_mlp<<<16, 128, 0, stream>>>(seidel, m1_w1, m1_b1, m1_w2, m1_b2,
                                m2_w1, m2_b1, m2_w2, m2_b2, e_all);
  k_hyper<<<HYPER_OUT/256, 256, 0, stream>>>(e_all, hyper_w, hyper_b, wb_lin);
  k_repack<<<dim3(16, 72), 256, 0, stream>>>(wb_lin, wb);
  k_transpose<<<dim3(4, 2, 512), 256, 0, stream>>>(x, xt);

  k_conv<false><<<dim3(256, 2, 2), 256, 0, stream>>>(xt, wb, nullptr, nullptr, y1, ps, p2);
  k_bnapply<<<2, 128, 0, stream>>>(ps, p2, bn1_g, bn1_b, bn1_a, bn1_c);

  k_conv<true><<<dim3(256, 2, 2), 256, 0, stream>>>(y1, wb + 2359296,
                                                    bn1_a, bn1_c, y2, ps, p2);
  k_bnapply<<<2, 128, 0, stream>>>(ps, p2, bn2_g, bn2_b, bn2_a, bn2_c);
  k_final<<<dim3(4, 2, 512), 256, 0, stream>>>(y2, bn2_a, bn2_c, (float*)d_out);
}